// Round 19
// baseline (170.968 us; speedup 1.0000x reference)
//
#include <hip/hip_runtime.h>
#include <hip/hip_bf16.h>

#define BB 64
#define NN 6272      // H*W*C = 196*32
#define OO 10
#define TPB 320      // moments/transform block
#define EPSF 1e-9f
#define LOG2E 1.44269504f
#define HLOG2E 0.72134752f   // 0.5*log2(e)

#define EXP2F(x) __builtin_amdgcn_exp2f(x)   // v_exp_f32
#define RCPF(x)  __builtin_amdgcn_rcpf(x)    // v_rcp_f32 (2^-22 rel err, tol is 3.9e-3)

// workspace offsets (floats)
#define ACC_PER_IT 21120            // B*O*33
#define OFF_ACC 0                   // 3 * 21120 = 63360
#define OFF_GPART 63360             // B*7*2208 = 989184 (per-chunk partials)

// lgkmcnt-only workgroup barrier
__device__ __forceinline__ void lds_barrier() {
    asm volatile("s_waitcnt lgkmcnt(0)" ::: "memory");
    __builtin_amdgcn_s_barrier();
    asm volatile("" ::: "memory");
}

// ---------------- pass0a: moments accumulation (R24-proven, 7 chunks) ------
__global__ __launch_bounds__(TPB, 3) void fc_moments(
    const float* __restrict__ pose, const float* __restrict__ actv,
    float* __restrict__ gpart)
{
    __shared__ float smem0[5 * 2208];       // [wave][c][69] slices, 44160 B

    const int t = threadIdx.x;
    const int lane = t & 63;
    const int wv = t >> 6;                  // 0..4
    const int c = lane & 31;
    const int slot = t >> 5;                // 0..9
    const int chunk = blockIdx.x;           // 0..6 (28 hw rows each)
    const int b = blockIdx.y;

    float A1[16], M[40], Vw[4], Vh[4];
    float S0 = 0.f, Uw = 0.f, Uh = 0.f, sw2 = 0.f, sh2 = 0.f;
    #pragma unroll
    for (int k = 0; k < 16; k++) A1[k] = 0.f;
    #pragma unroll
    for (int k = 0; k < 40; k++) M[k] = 0.f;
    #pragma unroll
    for (int k = 0; k < 4; k++) { Vw[k] = 0.f; Vh[k] = 0.f; }

    // prefetch row r=0 (hl = slot, always < 28)
    float4 n0, n1, n2, n3; float na;
    {
        const int hw = chunk * 28 + slot;
        const size_t row = (size_t)b * NN + (hw << 5) + c;
        const float4* p = (const float4*)(pose + row * 16);
        n0 = p[0]; n1 = p[1]; n2 = p[2]; n3 = p[3];
        na = actv[row];
    }

    for (int r = 0; r < 3; r++) {
        const int hl = slot + 10 * r;
        if (hl >= 28) break;                 // slots 8,9 do 2 rows

        const float4 q0 = n0, q1 = n1, q2 = n2, q3 = n3;
        const float aq = na;

        // prefetch next row before folding this one
        const int hln = hl + 10;
        if (hln < 28) {
            const int hwn = chunk * 28 + hln;
            const size_t rown = (size_t)b * NN + (hwn << 5) + c;
            const float4* p = (const float4*)(pose + rown * 16);
            n0 = p[0]; n1 = p[1]; n2 = p[2]; n3 = p[3];
            na = actv[rown];
        }

        const int hw = chunk * 28 + hl;
        const int hi = hw / 14;
        const int wi = hw - hi * 14;
        const float offw = (wi + 0.5f) * (1.0f / 14.0f);
        const float offh = (hi + 0.5f) * (1.0f / 14.0f);

        const float ra = 0.1f * aq;
        const float raw = ra * offw, rah = ra * offh;
        S0 += ra; Uw += raw; Uh += rah;
        sw2 = fmaf(raw, offw, sw2); sh2 = fmaf(rah, offh, sh2);

        #define FOLD_I(qq, i)                                              \
        {                                                                  \
            const float x = qq.x, y = qq.y, z = qq.z, w = qq.w;            \
            const float t0 = ra * x, t1 = ra * y, t2 = ra * z, t3 = ra * w;\
            A1[i*4+0] += t0; A1[i*4+1] += t1;                              \
            A1[i*4+2] += t2; A1[i*4+3] += t3;                              \
            M[i*10+0] = fmaf(t0, x, M[i*10+0]);                            \
            M[i*10+1] = fmaf(t0, y, M[i*10+1]);                            \
            M[i*10+2] = fmaf(t0, z, M[i*10+2]);                            \
            M[i*10+3] = fmaf(t0, w, M[i*10+3]);                            \
            M[i*10+4] = fmaf(t1, y, M[i*10+4]);                            \
            M[i*10+5] = fmaf(t1, z, M[i*10+5]);                            \
            M[i*10+6] = fmaf(t1, w, M[i*10+6]);                            \
            M[i*10+7] = fmaf(t2, z, M[i*10+7]);                            \
            M[i*10+8] = fmaf(t2, w, M[i*10+8]);                            \
            M[i*10+9] = fmaf(t3, w, M[i*10+9]);                            \
        }
        FOLD_I(q0, 0) FOLD_I(q1, 1) FOLD_I(q2, 2) FOLD_I(q3, 3)
        #undef FOLD_I
        Vw[0] = fmaf(raw, q0.x, Vw[0]); Vw[1] = fmaf(raw, q0.y, Vw[1]);
        Vw[2] = fmaf(raw, q0.z, Vw[2]); Vw[3] = fmaf(raw, q0.w, Vw[3]);
        Vh[0] = fmaf(rah, q1.x, Vh[0]); Vh[1] = fmaf(rah, q1.y, Vh[1]);
        Vh[2] = fmaf(rah, q1.z, Vh[2]); Vh[3] = fmaf(rah, q1.w, Vh[3]);
    }

    float* myrow = &smem0[wv * 2208 + c * 69];
    #define FOLDW(arr, n, base)                                            \
    _Pragma("unroll")                                                      \
    for (int k2 = 0; k2 < n; k2++) {                                       \
        float x = arr[k2] + __shfl_xor(arr[k2], 32, 64);                   \
        if (lane < 32) myrow[base + k2] = x;                               \
    }
    FOLDW(A1, 16, 0) FOLDW(M, 40, 16) FOLDW(Vw, 4, 56) FOLDW(Vh, 4, 60)
    #undef FOLDW
    {
        float x0 = S0 + __shfl_xor(S0, 32, 64);
        float x1 = Uw + __shfl_xor(Uw, 32, 64);
        float x2 = Uh + __shfl_xor(Uh, 32, 64);
        float x3 = sw2 + __shfl_xor(sw2, 32, 64);
        float x4 = sh2 + __shfl_xor(sh2, 32, 64);
        if (lane < 32) {
            myrow[64] = x0; myrow[65] = x1; myrow[66] = x2;
            myrow[67] = x3; myrow[68] = x4;
        }
    }
    __syncthreads();
    float* gb = gpart + ((size_t)b * 7 + chunk) * 2208;
    for (int e = t; e < 2208; e += TPB) {
        gb[e] = smem0[e] + smem0[2208 + e] + smem0[2*2208 + e]
              + smem0[3*2208 + e] + smem0[4*2208 + e];
    }
}

// ---------------- pass0b: transform, ONCE per b (grid 64) ----------------
__global__ __launch_bounds__(TPB) void fc_transform(
    const float* __restrict__ gpart, const float* __restrict__ wgt,
    float* __restrict__ acc)
{
    __shared__ float smem0[2208];
    const int t = threadIdx.x;
    const int b = blockIdx.x;

    // zero this b's acc1/acc2 slices (fc_pass epilogues atomicAdd into them)
    {
        float* z1 = acc + ACC_PER_IT + (size_t)b * OO * 33;
        float* z2 = acc + 2 * ACC_PER_IT + (size_t)b * OO * 33;
        for (int e = t; e < 330; e += TPB) { z1[e] = 0.f; z2[e] = 0.f; }
    }

    const float* gb = gpart + (size_t)b * 7 * 2208;
    for (int e = t; e < 2208; e += TPB) {
        float s = 0.f;
        #pragma unroll
        for (int ch = 0; ch < 7; ch++) s += gb[ch * 2208 + e];
        smem0[e] = s;
    }
    __syncthreads();

    const int oo = t >> 5, k = t & 31;
    float* ab = acc + ((size_t)b * OO + oo) * 33;
    if (k < 16) {
        const int i = k >> 2, kk = k & 3;
        float s = 0.f, s0acc = 0.f;
        #pragma unroll 4
        for (int cc = 0; cc < 32; cc++) {
            const float* mc = &smem0[cc * 69];
            const float* wc = wgt + cc * 160 + oo * 16 + kk;
            const float w0 = wc[0], w1 = wc[4], w2 = wc[8], w3 = wc[12];
            s += w0*mc[i*4+0] + w1*mc[i*4+1] + w2*mc[i*4+2] + w3*mc[i*4+3];
            if (k == 3) s += mc[65];
            if (k == 7) s += mc[66];
            if (k == 0) s0acc += mc[64];
        }
        ab[k] = s;
        if (k == 0) ab[32] = s0acc;
    } else {
        const int km = k - 16, i = km >> 2, kk = km & 3;
        float s = 0.f;
        #pragma unroll 4
        for (int cc = 0; cc < 32; cc++) {
            const float* mc = &smem0[cc * 69];
            const float* mi = mc + 16 + i * 10;
            const float* wc = wgt + cc * 160 + oo * 16 + kk;
            const float w0 = wc[0], w1 = wc[4], w2 = wc[8], w3 = wc[12];
            float q = w0*(w0*mi[0] + 2.f*(w1*mi[1] + w2*mi[2] + w3*mi[3]))
                    + w1*(w1*mi[4] + 2.f*(w2*mi[5] + w3*mi[6]))
                    + w2*(w2*mi[7] + 2.f*w3*mi[8])
                    + w3*(w3*mi[9]);
            s += q;
            if (km == 3) s += 2.f*(w0*mc[56]+w1*mc[57]+w2*mc[58]+w3*mc[59]) + mc[67];
            if (km == 7) s += 2.f*(w0*mc[60]+w1*mc[61]+w2*mc[62]+w3*mc[63]) + mc[68];
        }
        ab[k] = s;
    }
}

// ---------------- iters 1-2: R27 = R24 body, wr in LDS, 9 steps ------------
// R23/R24 established fc_pass is latency-bound with VGPR 68 capping
// residency at 4 waves/SIMD. R27 drops wr[16] from registers: the votes
// matmul reads the 4x4 weight ROW-BY-ROW from LDS (4x ds_read_b128/step,
// v accumulates across rows => only 4 weight floats live at once). Target
// VGPR <=64 => 8 waves/SIMD; grid 32x64 (49-row/9-step chunks) supplies
// 8 blocks/CU to use it. wrL/ivL/m2L/bL alias into the epilogue-table LDS
// (dead by epilogue; barrier added before epilogue writes to prevent a
// fast-wave overwrite race). wrL stride 20 => 2-way bank alias (free).
// TRIPWIRE: if VGPR_Count > 64 this is a known regression (~47us/pass).
__global__ __launch_bounds__(256) void fc_pass(
    const float* __restrict__ pose, const float* __restrict__ actv,
    const float* __restrict__ wgt,
    const float* __restrict__ accPrev,
    const float* __restrict__ beta_a, const float* __restrict__ beta_u,
    float* __restrict__ accOut, float inv_temp)
{
    __shared__ float smem[256 * 17];    // epilogue table; preamble aliases below
    float* wrL = smem;                  // 40 rows x stride 20 = 800 floats
    float* ivL = smem + 800;            // 10 x 36 padded = 360
    float* m2L = smem + 1160;           // 10 x 36 padded = 360
    float* bL  = smem + 1520;           // [o]=bias2, [10]=UBs

    const int t = threadIdx.x;
    const int lane = t & 63;
    const int w4 = t >> 6;              // wave 0..3
    const int nl = lane / 10;           // 0..6 (6 => idle lanes 60-63)
    const int o = lane - nl * 10;       // 0..9
    const bool lanereal = (nl < 6);
    const int gbase = (lanereal ? nl : 0) * 10;   // idle lanes mirror group 0

    const int bx = blockIdx.x;          // 0..31
    const int chunk = bx >> 3;          // 0..3 (49 hw each)
    const int c = ((bx & 7) << 2) + w4; // 0..31, fixed per wave
    const int b = blockIdx.y;

    const int hwbase = chunk * 49;
    const size_t rowbase = (size_t)b * NN + ((size_t)hwbase << 5) + c;

    // weight row (c,o) -> LDS, written once by lanes nl==0 of each wave
    if (nl == 0) {
        const float4* wp = (const float4*)(wgt + ((c * OO + o) << 4));
        float4 a0 = wp[0], a1 = wp[1], a2 = wp[2], a3 = wp[3];
        float* dst = &wrL[(w4 * 10 + o) * 20];
        *(float4*)(dst + 0)  = a0;
        *(float4*)(dst + 4)  = a1;
        *(float4*)(dst + 8)  = a2;
        *(float4*)(dst + 12) = a3;
    }

    // stats computed by t<10 only (lane==t, o==t, all in wave 0)
    if (t < 10) {
        const float* ab = accPrev + ((size_t)b * OO + t) * 33;
        const float S0p = ab[32];
        const float rs = S0p + EPSF;
        const float rsi = RCPF(rs);
        float sv = 0.f, csum = 0.f;
        #pragma unroll
        for (int d = 0; d < 16; d++) {
            const float s1 = ab[d], s2 = ab[16 + d];
            const float m = s1 * rsi;
            float vraw = fmaf(m * m, S0p, fmaf(-2.f * m, s1, s2));
            vraw = fmaxf(vraw, 0.f);
            const float var = fmaf(vraw, rsi, EPSF);
            sv += __logf(var);
            const float ivd = RCPF(var);
            const float i2 = ivd * HLOG2E;
            ivL[t * 36 + d] = i2;
            m2L[t * 36 + d] = 2.f * m * i2;
            csum = fmaf(m * m, i2, csum);
        }
        const float cost = rs * fmaf(0.5f, sv, 16.f * beta_u[t]);
        const float act = RCPF(1.f + __expf(-inv_temp * (beta_a[t] - cost)));
        const float biasN = __logf(act + EPSF) - 0.5f * sv;
        const float biasL = biasN * LOG2E;
        bL[t] = biasL - csum;
        float ub = biasL;
        #pragma unroll
        for (int j = 0; j < OO; j++) ub = fmaxf(ub, __shfl(biasL, j, 64));
        if (t == 0) bL[10] = ub - 64.f;   // +64 headroom vs underflow
    }
    lds_barrier();

    float iv2[16], m2iv[16];
    {
        const float4* ip = (const float4*)&ivL[o * 36];   // 36%4==0: aligned
        float4 x0 = ip[0], x1 = ip[1], x2 = ip[2], x3 = ip[3];
        iv2[0]=x0.x; iv2[1]=x0.y; iv2[2]=x0.z; iv2[3]=x0.w;
        iv2[4]=x1.x; iv2[5]=x1.y; iv2[6]=x1.z; iv2[7]=x1.w;
        iv2[8]=x2.x; iv2[9]=x2.y; iv2[10]=x2.z; iv2[11]=x2.w;
        iv2[12]=x3.x; iv2[13]=x3.y; iv2[14]=x3.z; iv2[15]=x3.w;
        const float4* mp = (const float4*)&m2L[o * 36];
        float4 y0 = mp[0], y1 = mp[1], y2 = mp[2], y3 = mp[3];
        m2iv[0]=y0.x; m2iv[1]=y0.y; m2iv[2]=y0.z; m2iv[3]=y0.w;
        m2iv[4]=y1.x; m2iv[5]=y1.y; m2iv[6]=y1.z; m2iv[7]=y1.w;
        m2iv[8]=y2.x; m2iv[9]=y2.y; m2iv[10]=y2.z; m2iv[11]=y2.w;
        m2iv[12]=y3.x; m2iv[13]=y3.y; m2iv[14]=y3.z; m2iv[15]=y3.w;
    }
    const float bias2 = bL[o];
    const float UBs = bL[10];
    const float* wrow = &wrL[(w4 * 10 + o) * 20];

    float S1[16], S2[16], S0 = 0.f;
    #pragma unroll
    for (int d = 0; d < 16; d++) { S1[d] = 0.f; S2[d] = 0.f; }

    for (int step = 0; step < 9; ++step) {
        const int hl = step * 6 + nl;                  // 0..52
        const bool valid = lanereal && (hl < 49);
        const int hle = valid ? hl : 0;                // clamp for address
        const int hw = hwbase + hle;                   // < 196
        const size_t row = rowbase + ((size_t)hle << 5);

        const float4* pp = (const float4*)(pose + row * 16);
        float4 q0 = pp[0], q1 = pp[1], q2 = pp[2], q3 = pp[3];
        const float a = valid ? actv[row] : 0.f;       // rr=0 for dead lanes

        const int hq = hw / 14;                        // magic-div, hw<196
        const float offw = ((hw - hq * 14) + 0.5f) * (1.0f / 14.0f);
        const float offh = (hq + 0.5f) * (1.0f / 14.0f);

        float p[16];
        p[0]=q0.x; p[1]=q0.y; p[2]=q0.z; p[3]=q0.w;
        p[4]=q1.x; p[5]=q1.y; p[6]=q1.z; p[7]=q1.w;
        p[8]=q2.x; p[9]=q2.y; p[10]=q2.z; p[11]=q2.w;
        p[12]=q3.x; p[13]=q3.y; p[14]=q3.z; p[15]=q3.w;

        // votes: v[ii*4+kk] = sum_dd p[ii*4+dd]*wr[dd*4+kk], weight rows
        // streamed from LDS (4 floats live at a time)
        float v[16];
        #pragma unroll
        for (int k2 = 0; k2 < 16; k2++) v[k2] = 0.f;
        v[3] = offw; v[7] = offh;
        #pragma unroll
        for (int dd = 0; dd < 4; dd++) {
            const float4 wf = *(const float4*)(wrow + dd * 4);
            #pragma unroll
            for (int ii = 0; ii < 4; ii++) {
                v[ii*4+0] = fmaf(p[ii*4+dd], wf.x, v[ii*4+0]);
                v[ii*4+1] = fmaf(p[ii*4+dd], wf.y, v[ii*4+1]);
                v[ii*4+2] = fmaf(p[ii*4+dd], wf.z, v[ii*4+2]);
                v[ii*4+3] = fmaf(p[ii*4+dd], wf.w, v[ii*4+3]);
            }
        }

        // lg2 = bias2 + sum_d v*(m2iv - v*iv2)
        float pa = 0.f, pb = 0.f, pc = 0.f, pd = 0.f;
        #pragma unroll
        for (int ii = 0; ii < 4; ii++) {
            float t0 = fmaf(-v[ii*4+0], iv2[ii*4+0], m2iv[ii*4+0]);
            float t1 = fmaf(-v[ii*4+1], iv2[ii*4+1], m2iv[ii*4+1]);
            float t2 = fmaf(-v[ii*4+2], iv2[ii*4+2], m2iv[ii*4+2]);
            float t3 = fmaf(-v[ii*4+3], iv2[ii*4+3], m2iv[ii*4+3]);
            pa = fmaf(v[ii*4+0], t0, pa);
            pb = fmaf(v[ii*4+1], t1, pb);
            pc = fmaf(v[ii*4+2], t2, pc);
            pd = fmaf(v[ii*4+3], t3, pd);
        }
        const float lg = bias2 + ((pa + pb) + (pc + pd));

        // static-UB softmax: 1 exp2 per lane, gather the 10 efs in-wave
        const float ef = EXP2F(lg - UBs);
        float efs[OO];
        #pragma unroll
        for (int j = 0; j < OO; j++) efs[j] = __shfl(ef, gbase + j, 64);
        float s01 = efs[0]+efs[1], s23 = efs[2]+efs[3], s45 = efs[4]+efs[5];
        float s67 = efs[6]+efs[7], s89 = efs[8]+efs[9];
        const float sum = (((s01+s23) + (s45+s67)) + s89) + 1e-30f;
        const float rr = ef * (a * RCPF(sum));

        #pragma unroll
        for (int d = 0; d < 16; d++) {
            const float rv = rr * v[d];
            S1[d] += rv;
            S2[d] = fmaf(rv, v[d], S2[d]);
        }
        S0 += rr;
    }

    // ---- epilogue: two-round LDS table (256x17) + atomics ----
    // barrier BEFORE overwriting the aliased wrL region (slow waves may
    // still be reading weight rows in their last step)
    lds_barrier();
    float* accB = accOut + (size_t)b * OO * 33;
    #pragma unroll
    for (int k = 0; k < 16; k++) smem[t * 17 + k] = S1[k];
    smem[t * 17 + 16] = S0;
    __syncthreads();
    for (int u = t; u < 170; u += 256) {
        const int oo = u / 17, kk = u - 17 * oo;
        float s = 0.f;
        #pragma unroll
        for (int wq = 0; wq < 4; wq++) {
            #pragma unroll
            for (int nn = 0; nn < 6; nn++)
                s += smem[(wq * 64 + nn * 10 + oo) * 17 + kk];
        }
        atomicAdd(accB + oo * 33 + ((kk < 16) ? kk : 32), s);
    }
    __syncthreads();
    #pragma unroll
    for (int k = 0; k < 16; k++) smem[t * 17 + k] = S2[k];
    __syncthreads();
    for (int u = t; u < 160; u += 256) {
        const int oo = u >> 4, kk = u & 15;
        float s = 0.f;
        #pragma unroll
        for (int wq = 0; wq < 4; wq++) {
            #pragma unroll
            for (int nn = 0; nn < 6; nn++)
                s += smem[(wq * 64 + nn * 10 + oo) * 17 + kk];
        }
        atomicAdd(accB + oo * 33 + 16 + kk, s);
    }
}

__global__ __launch_bounds__(256) void fc_stats(
    const float* __restrict__ acc, const float* __restrict__ beta_a,
    const float* __restrict__ beta_u,
    float* __restrict__ out, float inv_temp)
{
    const int t = threadIdx.x;
    const int b = blockIdx.x;
    if (t >= 160) return;
    const int o = t >> 4, d = t & 15;
    const float* ab = acc + ((size_t)b * OO + o) * 33;
    const float S1 = ab[d], S2 = ab[16 + d], S0 = ab[32];
    const float rs = S0 + EPSF;
    const float mu = S1 / rs;
    float vraw = fmaf(mu * mu, S0, fmaf(-2.f * mu, S1, S2));
    vraw = fmaxf(vraw, 0.f);
    const float var = vraw / rs + EPSF;
    const float lv = __logf(var);
    float sv = lv;
    #pragma unroll
    for (int off = 8; off >= 1; off >>= 1) sv += __shfl_xor(sv, off, 16);
    const float cost = rs * fmaf(0.5f, sv, 16.f * beta_u[o]);
    const float av = 1.f / (1.f + __expf(-inv_temp * (beta_a[o] - cost)));
    out[((size_t)b * OO + o) * 16 + d] = mu;               // pose_out (B,O,16)
    if (d == 0) out[BB * OO * 16 + b * OO + o] = av;       // act_out (B,O)
}

extern "C" void kernel_launch(void* const* d_in, const int* in_sizes, int n_in,
                              void* d_out, int out_size, void* d_ws, size_t ws_size,
                              hipStream_t stream) {
    const float* pose   = (const float*)d_in[0];
    const float* actv   = (const float*)d_in[1];
    const float* wgt    = (const float*)d_in[2];
    const float* beta_a = (const float*)d_in[3];
    const float* beta_u = (const float*)d_in[4];
    float* out = (float*)d_out;
    float* ws  = (float*)d_ws;

    float* acc0  = ws + OFF_ACC;
    float* acc1  = ws + OFF_ACC + ACC_PER_IT;
    float* acc2  = ws + OFF_ACC + 2 * ACC_PER_IT;
    float* gpart = ws + OFF_GPART;

    // no memset: fc_transform zeroes acc1/acc2; gpart fully written by
    // fc_moments (plain stores, no atomics).
    fc_moments<<<dim3(7, BB), dim3(TPB), 0, stream>>>(pose, actv, gpart);
    fc_transform<<<BB, dim3(TPB), 0, stream>>>(gpart, wgt, acc0);
    fc_pass<<<dim3(32, BB), dim3(256), 0, stream>>>(pose, actv, wgt, acc0, beta_a, beta_u, acc1, 1.0f);
    fc_pass<<<dim3(32, BB), dim3(256), 0, stream>>>(pose, actv, wgt, acc1, beta_a, beta_u, acc2, 2.0f);
    fc_stats<<<BB, 256, 0, stream>>>(acc2, beta_a, beta_u, out, 3.0f);
}

// Round 20
// 162.299 us; speedup vs baseline: 1.0534x; 1.0534x over previous
//
#include <hip/hip_runtime.h>
#include <hip/hip_bf16.h>

#define BB 64
#define NN 6272      // H*W*C = 196*32
#define OO 10
#define TPB 320      // moments/transform block
#define EPSF 1e-9f
#define LOG2E 1.44269504f
#define HLOG2E 0.72134752f   // 0.5*log2(e)

#define EXP2F(x) __builtin_amdgcn_exp2f(x)   // v_exp_f32
#define RCPF(x)  __builtin_amdgcn_rcpf(x)    // v_rcp_f32 (2^-22 rel err, tol is 3.9e-3)

// workspace offsets (floats)
#define ACC_PER_IT 21120            // B*O*33
#define OFF_ACC 0                   // 3 * 21120 = 63360
#define OFF_GPART 63360             // B*7*2208 = 989184 (per-chunk partials)

// lgkmcnt-only workgroup barrier
__device__ __forceinline__ void lds_barrier() {
    asm volatile("s_waitcnt lgkmcnt(0)" ::: "memory");
    __builtin_amdgcn_s_barrier();
    asm volatile("" ::: "memory");
}

// ---------------- pass0a: moments accumulation (R24-proven, 7 chunks) ------
__global__ __launch_bounds__(TPB, 3) void fc_moments(
    const float* __restrict__ pose, const float* __restrict__ actv,
    float* __restrict__ gpart)
{
    __shared__ float smem0[5 * 2208];       // [wave][c][69] slices, 44160 B

    const int t = threadIdx.x;
    const int lane = t & 63;
    const int wv = t >> 6;                  // 0..4
    const int c = lane & 31;
    const int slot = t >> 5;                // 0..9
    const int chunk = blockIdx.x;           // 0..6 (28 hw rows each)
    const int b = blockIdx.y;

    float A1[16], M[40], Vw[4], Vh[4];
    float S0 = 0.f, Uw = 0.f, Uh = 0.f, sw2 = 0.f, sh2 = 0.f;
    #pragma unroll
    for (int k = 0; k < 16; k++) A1[k] = 0.f;
    #pragma unroll
    for (int k = 0; k < 40; k++) M[k] = 0.f;
    #pragma unroll
    for (int k = 0; k < 4; k++) { Vw[k] = 0.f; Vh[k] = 0.f; }

    // prefetch row r=0 (hl = slot, always < 28)
    float4 n0, n1, n2, n3; float na;
    {
        const int hw = chunk * 28 + slot;
        const size_t row = (size_t)b * NN + (hw << 5) + c;
        const float4* p = (const float4*)(pose + row * 16);
        n0 = p[0]; n1 = p[1]; n2 = p[2]; n3 = p[3];
        na = actv[row];
    }

    for (int r = 0; r < 3; r++) {
        const int hl = slot + 10 * r;
        if (hl >= 28) break;                 // slots 8,9 do 2 rows

        const float4 q0 = n0, q1 = n1, q2 = n2, q3 = n3;
        const float aq = na;

        // prefetch next row before folding this one
        const int hln = hl + 10;
        if (hln < 28) {
            const int hwn = chunk * 28 + hln;
            const size_t rown = (size_t)b * NN + (hwn << 5) + c;
            const float4* p = (const float4*)(pose + rown * 16);
            n0 = p[0]; n1 = p[1]; n2 = p[2]; n3 = p[3];
            na = actv[rown];
        }

        const int hw = chunk * 28 + hl;
        const int hi = hw / 14;
        const int wi = hw - hi * 14;
        const float offw = (wi + 0.5f) * (1.0f / 14.0f);
        const float offh = (hi + 0.5f) * (1.0f / 14.0f);

        const float ra = 0.1f * aq;
        const float raw = ra * offw, rah = ra * offh;
        S0 += ra; Uw += raw; Uh += rah;
        sw2 = fmaf(raw, offw, sw2); sh2 = fmaf(rah, offh, sh2);

        #define FOLD_I(qq, i)                                              \
        {                                                                  \
            const float x = qq.x, y = qq.y, z = qq.z, w = qq.w;            \
            const float t0 = ra * x, t1 = ra * y, t2 = ra * z, t3 = ra * w;\
            A1[i*4+0] += t0; A1[i*4+1] += t1;                              \
            A1[i*4+2] += t2; A1[i*4+3] += t3;                              \
            M[i*10+0] = fmaf(t0, x, M[i*10+0]);                            \
            M[i*10+1] = fmaf(t0, y, M[i*10+1]);                            \
            M[i*10+2] = fmaf(t0, z, M[i*10+2]);                            \
            M[i*10+3] = fmaf(t0, w, M[i*10+3]);                            \
            M[i*10+4] = fmaf(t1, y, M[i*10+4]);                            \
            M[i*10+5] = fmaf(t1, z, M[i*10+5]);                            \
            M[i*10+6] = fmaf(t1, w, M[i*10+6]);                            \
            M[i*10+7] = fmaf(t2, z, M[i*10+7]);                            \
            M[i*10+8] = fmaf(t2, w, M[i*10+8]);                            \
            M[i*10+9] = fmaf(t3, w, M[i*10+9]);                            \
        }
        FOLD_I(q0, 0) FOLD_I(q1, 1) FOLD_I(q2, 2) FOLD_I(q3, 3)
        #undef FOLD_I
        Vw[0] = fmaf(raw, q0.x, Vw[0]); Vw[1] = fmaf(raw, q0.y, Vw[1]);
        Vw[2] = fmaf(raw, q0.z, Vw[2]); Vw[3] = fmaf(raw, q0.w, Vw[3]);
        Vh[0] = fmaf(rah, q1.x, Vh[0]); Vh[1] = fmaf(rah, q1.y, Vh[1]);
        Vh[2] = fmaf(rah, q1.z, Vh[2]); Vh[3] = fmaf(rah, q1.w, Vh[3]);
    }

    float* myrow = &smem0[wv * 2208 + c * 69];
    #define FOLDW(arr, n, base)                                            \
    _Pragma("unroll")                                                      \
    for (int k2 = 0; k2 < n; k2++) {                                       \
        float x = arr[k2] + __shfl_xor(arr[k2], 32, 64);                   \
        if (lane < 32) myrow[base + k2] = x;                               \
    }
    FOLDW(A1, 16, 0) FOLDW(M, 40, 16) FOLDW(Vw, 4, 56) FOLDW(Vh, 4, 60)
    #undef FOLDW
    {
        float x0 = S0 + __shfl_xor(S0, 32, 64);
        float x1 = Uw + __shfl_xor(Uw, 32, 64);
        float x2 = Uh + __shfl_xor(Uh, 32, 64);
        float x3 = sw2 + __shfl_xor(sw2, 32, 64);
        float x4 = sh2 + __shfl_xor(sh2, 32, 64);
        if (lane < 32) {
            myrow[64] = x0; myrow[65] = x1; myrow[66] = x2;
            myrow[67] = x3; myrow[68] = x4;
        }
    }
    __syncthreads();
    float* gb = gpart + ((size_t)b * 7 + chunk) * 2208;
    for (int e = t; e < 2208; e += TPB) {
        gb[e] = smem0[e] + smem0[2208 + e] + smem0[2*2208 + e]
              + smem0[3*2208 + e] + smem0[4*2208 + e];
    }
}

// ---------------- pass0b: transform, ONCE per b (grid 64) ----------------
// Sums 7 chunk partials; zeroes acc1+acc2 so no host memset dispatch.
__global__ __launch_bounds__(TPB) void fc_transform(
    const float* __restrict__ gpart, const float* __restrict__ wgt,
    float* __restrict__ acc)
{
    __shared__ float smem0[2208];
    const int t = threadIdx.x;
    const int b = blockIdx.x;

    // zero this b's acc1/acc2 slices (fc_pass epilogues atomicAdd into them)
    {
        float* z1 = acc + ACC_PER_IT + (size_t)b * OO * 33;
        float* z2 = acc + 2 * ACC_PER_IT + (size_t)b * OO * 33;
        for (int e = t; e < 330; e += TPB) { z1[e] = 0.f; z2[e] = 0.f; }
    }

    const float* gb = gpart + (size_t)b * 7 * 2208;
    for (int e = t; e < 2208; e += TPB) {
        float s = 0.f;
        #pragma unroll
        for (int ch = 0; ch < 7; ch++) s += gb[ch * 2208 + e];
        smem0[e] = s;
    }
    __syncthreads();

    const int oo = t >> 5, k = t & 31;
    float* ab = acc + ((size_t)b * OO + oo) * 33;
    if (k < 16) {
        const int i = k >> 2, kk = k & 3;
        float s = 0.f, s0acc = 0.f;
        #pragma unroll 4
        for (int cc = 0; cc < 32; cc++) {
            const float* mc = &smem0[cc * 69];
            const float* wc = wgt + cc * 160 + oo * 16 + kk;
            const float w0 = wc[0], w1 = wc[4], w2 = wc[8], w3 = wc[12];
            s += w0*mc[i*4+0] + w1*mc[i*4+1] + w2*mc[i*4+2] + w3*mc[i*4+3];
            if (k == 3) s += mc[65];
            if (k == 7) s += mc[66];
            if (k == 0) s0acc += mc[64];
        }
        ab[k] = s;
        if (k == 0) ab[32] = s0acc;
    } else {
        const int km = k - 16, i = km >> 2, kk = km & 3;
        float s = 0.f;
        #pragma unroll 4
        for (int cc = 0; cc < 32; cc++) {
            const float* mc = &smem0[cc * 69];
            const float* mi = mc + 16 + i * 10;
            const float* wc = wgt + cc * 160 + oo * 16 + kk;
            const float w0 = wc[0], w1 = wc[4], w2 = wc[8], w3 = wc[12];
            float q = w0*(w0*mi[0] + 2.f*(w1*mi[1] + w2*mi[2] + w3*mi[3]))
                    + w1*(w1*mi[4] + 2.f*(w2*mi[5] + w3*mi[6]))
                    + w2*(w2*mi[7] + 2.f*w3*mi[8])
                    + w3*(w3*mi[9]);
            s += q;
            if (km == 3) s += 2.f*(w0*mc[56]+w1*mc[57]+w2*mc[58]+w3*mc[59]) + mc[67];
            if (km == 7) s += 2.f*(w0*mc[60]+w1*mc[61]+w2*mc[62]+w3*mc[63]) + mc[68];
        }
        ab[k] = s;
    }
}

// ---------------- iters 1-2: R24 fc_pass (proven best) ---------------------
// Barrier-free wave-local softmax (R19), 98-row/17-step amortized chunks
// (R21), static-UB softmax (R23), split stats preamble (R24). All other
// axes tested bidirectionally and regressed (R20 prefetch, R22/R25 grid,
// R14/R16 ILP-spill, R27 wr-in-LDS).
__global__ __launch_bounds__(256) void fc_pass(
    const float* __restrict__ pose, const float* __restrict__ actv,
    const float* __restrict__ wgt,
    const float* __restrict__ accPrev,
    const float* __restrict__ beta_a, const float* __restrict__ beta_u,
    float* __restrict__ accOut, float inv_temp)
{
    __shared__ float smem[256 * 17];    // epilogue table, 17408 B
    __shared__ float ivL[10 * 36];      // iv2 broadcast, padded
    __shared__ float m2L[10 * 36];      // m2iv broadcast, padded
    __shared__ float bL[12];            // [o]=bias2, [10]=UBs

    const int t = threadIdx.x;
    const int lane = t & 63;
    const int w4 = t >> 6;              // wave 0..3
    const int nl = lane / 10;           // 0..6 (6 => idle lanes 60-63)
    const int o = lane - nl * 10;       // 0..9
    const bool lanereal = (nl < 6);
    const int gbase = (lanereal ? nl : 0) * 10;   // idle lanes mirror group 0

    const int bx = blockIdx.x;          // 0..15
    const int chunk = bx >> 3;          // 0..1 (98 hw each)
    const int c = ((bx & 7) << 2) + w4; // 0..31, fixed per wave
    const int b = blockIdx.y;

    const int hwbase = chunk * 98;
    const size_t rowbase = (size_t)b * NN + ((size_t)hwbase << 5) + c;

    float wr[16];
    {
        const float4* wp = (const float4*)(wgt + ((c * OO + o) << 4));
        float4 a0 = wp[0], a1 = wp[1], a2 = wp[2], a3 = wp[3];
        wr[0]=a0.x; wr[1]=a0.y; wr[2]=a0.z; wr[3]=a0.w;
        wr[4]=a1.x; wr[5]=a1.y; wr[6]=a1.z; wr[7]=a1.w;
        wr[8]=a2.x; wr[9]=a2.y; wr[10]=a2.z; wr[11]=a2.w;
        wr[12]=a3.x; wr[13]=a3.y; wr[14]=a3.z; wr[15]=a3.w;
    }

    // stats computed by t<10 only (lane==t, o==t, all in wave 0)
    if (t < 10) {
        const float* ab = accPrev + ((size_t)b * OO + t) * 33;
        const float S0p = ab[32];
        const float rs = S0p + EPSF;
        const float rsi = RCPF(rs);
        float sv = 0.f, csum = 0.f;
        #pragma unroll
        for (int d = 0; d < 16; d++) {
            const float s1 = ab[d], s2 = ab[16 + d];
            const float m = s1 * rsi;
            float vraw = fmaf(m * m, S0p, fmaf(-2.f * m, s1, s2));
            vraw = fmaxf(vraw, 0.f);
            const float var = fmaf(vraw, rsi, EPSF);
            sv += __logf(var);
            const float ivd = RCPF(var);
            const float i2 = ivd * HLOG2E;
            ivL[t * 36 + d] = i2;
            m2L[t * 36 + d] = 2.f * m * i2;
            csum = fmaf(m * m, i2, csum);
        }
        const float cost = rs * fmaf(0.5f, sv, 16.f * beta_u[t]);
        const float act = RCPF(1.f + __expf(-inv_temp * (beta_a[t] - cost)));
        const float biasN = __logf(act + EPSF) - 0.5f * sv;
        const float biasL = biasN * LOG2E;
        bL[t] = biasL - csum;
        float ub = biasL;
        #pragma unroll
        for (int j = 0; j < OO; j++) ub = fmaxf(ub, __shfl(biasL, j, 64));
        if (t == 0) bL[10] = ub - 64.f;   // +64 headroom vs underflow
    }
    lds_barrier();

    float iv2[16], m2iv[16];
    {
        const float4* ip = (const float4*)&ivL[o * 36];   // 36%4==0: aligned
        float4 x0 = ip[0], x1 = ip[1], x2 = ip[2], x3 = ip[3];
        iv2[0]=x0.x; iv2[1]=x0.y; iv2[2]=x0.z; iv2[3]=x0.w;
        iv2[4]=x1.x; iv2[5]=x1.y; iv2[6]=x1.z; iv2[7]=x1.w;
        iv2[8]=x2.x; iv2[9]=x2.y; iv2[10]=x2.z; iv2[11]=x2.w;
        iv2[12]=x3.x; iv2[13]=x3.y; iv2[14]=x3.z; iv2[15]=x3.w;
        const float4* mp = (const float4*)&m2L[o * 36];
        float4 y0 = mp[0], y1 = mp[1], y2 = mp[2], y3 = mp[3];
        m2iv[0]=y0.x; m2iv[1]=y0.y; m2iv[2]=y0.z; m2iv[3]=y0.w;
        m2iv[4]=y1.x; m2iv[5]=y1.y; m2iv[6]=y1.z; m2iv[7]=y1.w;
        m2iv[8]=y2.x; m2iv[9]=y2.y; m2iv[10]=y2.z; m2iv[11]=y2.w;
        m2iv[12]=y3.x; m2iv[13]=y3.y; m2iv[14]=y3.z; m2iv[15]=y3.w;
    }
    const float bias2 = bL[o];
    const float UBs = bL[10];

    float S1[16], S2[16], S0 = 0.f;
    #pragma unroll
    for (int d = 0; d < 16; d++) { S1[d] = 0.f; S2[d] = 0.f; }

    for (int step = 0; step < 17; ++step) {
        const int hl = step * 6 + nl;                  // 0..101
        const bool valid = lanereal && (hl < 98);
        const int hle = valid ? hl : 0;                // clamp for address
        const int hw = hwbase + hle;                   // < 196
        const size_t row = rowbase + ((size_t)hle << 5);

        const float4* pp = (const float4*)(pose + row * 16);
        float4 q0 = pp[0], q1 = pp[1], q2 = pp[2], q3 = pp[3];
        const float a = valid ? actv[row] : 0.f;       // rr=0 for dead lanes

        const int hq = hw / 14;                        // magic-div, hw<196
        const float offw = ((hw - hq * 14) + 0.5f) * (1.0f / 14.0f);
        const float offh = (hq + 0.5f) * (1.0f / 14.0f);

        float p[16];
        p[0]=q0.x; p[1]=q0.y; p[2]=q0.z; p[3]=q0.w;
        p[4]=q1.x; p[5]=q1.y; p[6]=q1.z; p[7]=q1.w;
        p[8]=q2.x; p[9]=q2.y; p[10]=q2.z; p[11]=q2.w;
        p[12]=q3.x; p[13]=q3.y; p[14]=q3.z; p[15]=q3.w;

        float v[16];
        #pragma unroll
        for (int ii = 0; ii < 4; ii++) {
            #pragma unroll
            for (int kk = 0; kk < 4; kk++) {
                float vv = fmaf(p[ii*4+0], wr[0*4+kk],
                           fmaf(p[ii*4+1], wr[1*4+kk],
                           fmaf(p[ii*4+2], wr[2*4+kk],
                                p[ii*4+3] * wr[3*4+kk])));
                if (ii == 0 && kk == 3) vv += offw;
                if (ii == 1 && kk == 3) vv += offh;
                v[ii*4+kk] = vv;
            }
        }

        // lg2 = bias2 + sum_d v*(m2iv - v*iv2)
        float pa = 0.f, pb = 0.f, pc = 0.f, pd = 0.f;
        #pragma unroll
        for (int ii = 0; ii < 4; ii++) {
            float t0 = fmaf(-v[ii*4+0], iv2[ii*4+0], m2iv[ii*4+0]);
            float t1 = fmaf(-v[ii*4+1], iv2[ii*4+1], m2iv[ii*4+1]);
            float t2 = fmaf(-v[ii*4+2], iv2[ii*4+2], m2iv[ii*4+2]);
            float t3 = fmaf(-v[ii*4+3], iv2[ii*4+3], m2iv[ii*4+3]);
            pa = fmaf(v[ii*4+0], t0, pa);
            pb = fmaf(v[ii*4+1], t1, pb);
            pc = fmaf(v[ii*4+2], t2, pc);
            pd = fmaf(v[ii*4+3], t3, pd);
        }
        const float lg = bias2 + ((pa + pb) + (pc + pd));

        // static-UB softmax: 1 exp2 per lane, gather the 10 efs in-wave
        const float ef = EXP2F(lg - UBs);
        float efs[OO];
        #pragma unroll
        for (int j = 0; j < OO; j++) efs[j] = __shfl(ef, gbase + j, 64);
        float s01 = efs[0]+efs[1], s23 = efs[2]+efs[3], s45 = efs[4]+efs[5];
        float s67 = efs[6]+efs[7], s89 = efs[8]+efs[9];
        const float sum = (((s01+s23) + (s45+s67)) + s89) + 1e-30f;
        const float rr = ef * (a * RCPF(sum));

        #pragma unroll
        for (int d = 0; d < 16; d++) {
            const float rv = rr * v[d];
            S1[d] += rv;
            S2[d] = fmaf(rv, v[d], S2[d]);
        }
        S0 += rr;
    }

    // ---- epilogue: two-round LDS table (256x17) + atomics ----
    float* accB = accOut + (size_t)b * OO * 33;
    #pragma unroll
    for (int k = 0; k < 16; k++) smem[t * 17 + k] = S1[k];
    smem[t * 17 + 16] = S0;
    __syncthreads();
    for (int u = t; u < 170; u += 256) {
        const int oo = u / 17, kk = u - 17 * oo;
        float s = 0.f;
        #pragma unroll
        for (int wq = 0; wq < 4; wq++) {
            #pragma unroll
            for (int nn = 0; nn < 6; nn++)
                s += smem[(wq * 64 + nn * 10 + oo) * 17 + kk];
        }
        atomicAdd(accB + oo * 33 + ((kk < 16) ? kk : 32), s);
    }
    __syncthreads();
    #pragma unroll
    for (int k = 0; k < 16; k++) smem[t * 17 + k] = S2[k];
    __syncthreads();
    for (int u = t; u < 160; u += 256) {
        const int oo = u >> 4, kk = u & 15;
        float s = 0.f;
        #pragma unroll
        for (int wq = 0; wq < 4; wq++) {
            #pragma unroll
            for (int nn = 0; nn < 6; nn++)
                s += smem[(wq * 64 + nn * 10 + oo) * 17 + kk];
        }
        atomicAdd(accB + oo * 33 + 16 + kk, s);
    }
}

__global__ __launch_bounds__(256) void fc_stats(
    const float* __restrict__ acc, const float* __restrict__ beta_a,
    const float* __restrict__ beta_u,
    float* __restrict__ out, float inv_temp)
{
    const int t = threadIdx.x;
    const int b = blockIdx.x;
    if (t >= 160) return;
    const int o = t >> 4, d = t & 15;
    const float* ab = acc + ((size_t)b * OO + o) * 33;
    const float S1 = ab[d], S2 = ab[16 + d], S0 = ab[32];
    const float rs = S0 + EPSF;
    const float mu = S1 / rs;
    float vraw = fmaf(mu * mu, S0, fmaf(-2.f * mu, S1, S2));
    vraw = fmaxf(vraw, 0.f);
    const float var = vraw / rs + EPSF;
    const float lv = __logf(var);
    float sv = lv;
    #pragma unroll
    for (int off = 8; off >= 1; off >>= 1) sv += __shfl_xor(sv, off, 16);
    const float cost = rs * fmaf(0.5f, sv, 16.f * beta_u[o]);
    const float av = 1.f / (1.f + __expf(-inv_temp * (beta_a[o] - cost)));
    out[((size_t)b * OO + o) * 16 + d] = mu;               // pose_out (B,O,16)
    if (d == 0) out[BB * OO * 16 + b * OO + o] = av;       // act_out (B,O)
}

extern "C" void kernel_launch(void* const* d_in, const int* in_sizes, int n_in,
                              void* d_out, int out_size, void* d_ws, size_t ws_size,
                              hipStream_t stream) {
    const float* pose   = (const float*)d_in[0];
    const float* actv   = (const float*)d_in[1];
    const float* wgt    = (const float*)d_in[2];
    const float* beta_a = (const float*)d_in[3];
    const float* beta_u = (const float*)d_in[4];
    float* out = (float*)d_out;
    float* ws  = (float*)d_ws;

    float* acc0  = ws + OFF_ACC;
    float* acc1  = ws + OFF_ACC + ACC_PER_IT;
    float* acc2  = ws + OFF_ACC + 2 * ACC_PER_IT;
    float* gpart = ws + OFF_GPART;

    // no memset: fc_transform zeroes acc1/acc2; gpart fully written by
    // fc_moments (plain stores, no atomics).
    fc_moments<<<dim3(7, BB), dim3(TPB), 0, stream>>>(pose, actv, gpart);
    fc_transform<<<BB, dim3(TPB), 0, stream>>>(gpart, wgt, acc0);
    fc_pass<<<dim3(16, BB), dim3(256), 0, stream>>>(pose, actv, wgt, acc0, beta_a, beta_u, acc1, 1.0f);
    fc_pass<<<dim3(16, BB), dim3(256), 0, stream>>>(pose, actv, wgt, acc1, beta_a, beta_u, acc2, 2.0f);
    fc_stats<<<BB, 256, 0, stream>>>(acc2, beta_a, beta_u, out, 3.0f);
}